// Round 1
// baseline (104.613 us; speedup 1.0000x reference)
//
#include <hip/hip_runtime.h>
#include <hip/hip_bf16.h>

// Chamfer distance, B=4, N=M=8192, D=3, fp32.
// Strategy: per direction, min_m(||q-t||^2) = qn + min_m(tn - 2<q,t>).
// Stage (tx,ty,tz,tn) float4 tiles in LDS (broadcast reads), 4 queries/thread,
// 3 FMA + 1 fminf per pair. Cross-block min via flipped-uint atomicMin in ws,
// then a reduction kernel producing the scalar mean sum.

#define BATCH 4
#define NPTS 8192            // N == M
#define QPT 4                // queries per thread
#define BLK 256
#define QPB (QPT * BLK)      // 1024 queries per block
#define MC 1024              // targets staged per block
#define QCHUNKS (NPTS / QPB) // 8 query chunks per batch
#define TCHUNKS (NPTS / MC)  // 8 target chunks
#define TOTALQ (BATCH * NPTS)

__device__ __forceinline__ unsigned int flip_f32(float f) {
    unsigned int u = __float_as_uint(f);
    return (u & 0x80000000u) ? ~u : (u | 0x80000000u); // monotone ascending
}
__device__ __forceinline__ float unflip_f32(unsigned int u) {
    return (u & 0x80000000u) ? __uint_as_float(u ^ 0x80000000u)
                             : __uint_as_float(~u);
}

__global__ __launch_bounds__(BLK) void chamfer_min_kernel(
        const float* __restrict__ pred, const float* __restrict__ target,
        unsigned int* __restrict__ wsmin)
{
    const int dir = blockIdx.z;
    const float* __restrict__ Q  = (dir == 0) ? pred : target;
    const float* __restrict__ Tg = (dir == 0) ? target : pred;

    const int b  = blockIdx.x >> 3;       // QCHUNKS == 8
    const int qc = blockIdx.x & 7;

    __shared__ float4 tile[MC];           // 16 KB

    // ---- stage targets: (tx, ty, tz, tn) ----
    const int tbase = blockIdx.y * MC;
    #pragma unroll
    for (int k = 0; k < MC / BLK; ++k) {
        int j = threadIdx.x + k * BLK;
        const float* tp = Tg + ((size_t)b * NPTS + tbase + j) * 3;
        float tx = tp[0], ty = tp[1], tz = tp[2];
        tile[j] = make_float4(tx, ty, tz, tx * tx + ty * ty + tz * tz);
    }

    // ---- load queries ----
    float fx[QPT], fy[QPT], fz[QPT], qn[QPT], mn[QPT];
    int   qidx[QPT];
    #pragma unroll
    for (int k = 0; k < QPT; ++k) {
        int nl = qc * QPB + threadIdx.x + k * BLK;   // [0, NPTS)
        qidx[k] = b * NPTS + nl;                     // [0, TOTALQ)
        const float* qp = Q + (size_t)qidx[k] * 3;
        float x = qp[0], y = qp[1], z = qp[2];
        fx[k] = -2.0f * x; fy[k] = -2.0f * y; fz[k] = -2.0f * z;
        qn[k] = x * x + y * y + z * z;
        mn[k] = 3.4e38f;
    }
    __syncthreads();

    // ---- main loop: 3 FMA + 1 min per pair, LDS broadcast reads ----
    #pragma unroll 4
    for (int j = 0; j < MC; ++j) {
        float4 t = tile[j];
        #pragma unroll
        for (int k = 0; k < QPT; ++k) {
            float d = fmaf(fx[k], t.x, fmaf(fy[k], t.y, fmaf(fz[k], t.z, t.w)));
            mn[k] = fminf(mn[k], d);
        }
    }

    // ---- combine across target chunks ----
    const unsigned int base = (dir == 0) ? 0u : (unsigned int)TOTALQ;
    #pragma unroll
    for (int k = 0; k < QPT; ++k) {
        float total = mn[k] + qn[k];
        atomicMin(&wsmin[base + (unsigned int)qidx[k]], flip_f32(total));
    }
}

__global__ __launch_bounds__(BLK) void chamfer_reduce_kernel(
        const unsigned int* __restrict__ wsmin, float* __restrict__ out)
{
    const float inv = 1.0f / (float)TOTALQ;  // both means have 32768 elements
    float acc = 0.0f;
    for (int i = blockIdx.x * blockDim.x + threadIdx.x; i < 2 * TOTALQ;
         i += gridDim.x * blockDim.x) {
        acc += unflip_f32(wsmin[i]);
    }
    acc *= inv;
    // wave reduce (64 lanes)
    #pragma unroll
    for (int off = 32; off > 0; off >>= 1)
        acc += __shfl_down(acc, off, 64);
    __shared__ float wsum[BLK / 64];
    int lane = threadIdx.x & 63, wid = threadIdx.x >> 6;
    if (lane == 0) wsum[wid] = acc;
    __syncthreads();
    if (threadIdx.x == 0) {
        float s = 0.0f;
        #pragma unroll
        for (int w = 0; w < BLK / 64; ++w) s += wsum[w];
        atomicAdd(out, s);
    }
}

extern "C" void kernel_launch(void* const* d_in, const int* in_sizes, int n_in,
                              void* d_out, int out_size, void* d_ws, size_t ws_size,
                              hipStream_t stream) {
    const float* pred   = (const float*)d_in[0];
    const float* target = (const float*)d_in[1];
    float*       out    = (float*)d_out;
    unsigned int* wsmin = (unsigned int*)d_ws;

    // init: minima to +inf-encoding (0xFFFFFFFF), output accumulator to 0
    hipMemsetAsync(wsmin, 0xFF, (size_t)(2 * TOTALQ) * sizeof(unsigned int), stream);
    hipMemsetAsync(out, 0, sizeof(float), stream);

    dim3 grid(BATCH * QCHUNKS, TCHUNKS, 2);   // 32 x 8 x 2 = 512 blocks
    dim3 block(BLK);
    hipLaunchKernelGGL(chamfer_min_kernel, grid, block, 0, stream,
                       pred, target, wsmin);
    hipLaunchKernelGGL(chamfer_reduce_kernel, dim3(64), block, 0, stream,
                       wsmin, out);
}